// Round 1
// baseline (377.261 us; speedup 1.0000x reference)
//
#include <hip/hip_runtime.h>
#include <hip/hip_bf16.h>
#include <stdint.h>

// Problem constants
#define NATOMS 32768
#define DDIM   1024
#define HDIM   1024
#define ENUM   4
// R9: expert segments padded to 256 (was 128) so a 256-row GEMM tile never
// spans two experts. Worst-case padded M: pads sum to <= 768 and total must be
// a multiple of 256 -> Mpad <= 33536. Buffer cap 33792 (132*256) for slack.
#define MCAP   33792
#define MT256  132                 // launched m-tiles; runtime guard on meta Mpad

typedef unsigned short u16;
typedef unsigned char  u8;
typedef __attribute__((ext_vector_type(8)))  int   i32x8;
typedef __attribute__((ext_vector_type(16))) float f32x16;

// ---- workspace layout (bytes) ----
static const size_t XP_OFF   = 0;
static const size_t H1_OFF   = XP_OFF  + (size_t)MCAP * 1024;
static const size_t W1T_OFF  = H1_OFF  + (size_t)MCAP * 1024;
static const size_t W2T_OFF  = W1T_OFF + (size_t)ENUM * 1024 * 1024;
static const size_t PERM_OFF = W2T_OFF + (size_t)ENUM * 1024 * 1024;
static const size_t META_OFF = PERM_OFF + (size_t)MCAP * 4;
// meta ints: count[e] at e*16; cursor[e] at 64+e*16; offs[0..3] at 128..131;
// Mpad at 132; per-block count partials at 256 + b*4 + e  (b in [0,128))

__device__ __forceinline__ u8 f2fp8(float x) {
    int w = __builtin_amdgcn_cvt_pk_fp8_f32(x, x, 0, false);
    return (u8)(w & 0xFF);
}

// ------- count atoms per expert: per-block partials, no pre-zeroed meta -------
__global__ void k_count(const int* __restrict__ sym, int* __restrict__ meta) {
    __shared__ int cnt[4];
    int t = threadIdx.x;
    if (t < 4) cnt[t] = 0;
    __syncthreads();
    int n = blockIdx.x * 256 + t;
    int lane = t & 63;
    int e = sym[n];
#pragma unroll
    for (int j = 0; j < ENUM; ++j) {
        unsigned long long mask = __ballot(e == j);
        if (mask) {
            int leader = __ffsll((long long)mask) - 1;
            if (lane == leader) atomicAdd(&cnt[j], __popcll(mask));
        }
    }
    __syncthreads();
    if (t < 4) meta[256 + blockIdx.x * 4 + t] = cnt[t];
}

// -- sum partials; write counts/cursors/offs/Mpad; out = constant energy term --
__global__ void k_offsets(int* __restrict__ meta, const float* __restrict__ slope,
                          const float* __restrict__ b3, const float* __restrict__ inter,
                          float* __restrict__ out) {
    __shared__ int tot[4];
    int t = threadIdx.x;
    if (t < 4) {
        int s = 0;
#pragma unroll 8
        for (int b = 0; b < 128; ++b) s += meta[256 + b * 4 + t];
        tot[t] = s;
    }
    __syncthreads();
    if (t == 0) {
        int off = 0;
        float c = 0.f;
        for (int e = 0; e < 4; ++e) {
            int cnt = tot[e];
            meta[e * 16]     = cnt;   // total count
            meta[128 + e]    = off;   // segment start
            meta[64 + e*16]  = off;   // scatter cursor
            c += (float)cnt * (slope[e] * b3[e] + inter[e]);
            off += (cnt + 255) & ~255;   // R9: pad to 256 for 256-row tiles
        }
        meta[132] = off;              // Mpad
        out[0] = c;                   // per-atom constant terms, summed
    }
}

// ---------------- scatter atom ids (wave-aggregated: 4 atomics/wave) ----------------
__global__ void k_scatter(const int* __restrict__ sym, int* __restrict__ meta,
                          int* __restrict__ perm) {
    int n = blockIdx.x * 256 + threadIdx.x;
    int lane = threadIdx.x & 63;
    int e = sym[n];
#pragma unroll
    for (int j = 0; j < ENUM; ++j) {
        unsigned long long mask = __ballot(e == j);
        if (mask) {
            int leader = __ffsll((long long)mask) - 1;
            int base = 0;
            if (lane == leader)
                base = atomicAdd(&meta[64 + j * 16], __popcll(mask));
            base = __shfl(base, leader, 64);
            if (e == j) {
                int rank = __popcll(mask & ((1ull << lane) - 1ull));
                perm[base + rank] = n;
            }
        }
    }
}

// -------- features fp32 -> permuted fp8 (pad slots -> zeros, via offs/count) --------
__global__ void k_convx(const float* __restrict__ F, const int* __restrict__ perm,
                        const int* __restrict__ meta, u8* __restrict__ Xp) {
    int g = blockIdx.x * 256 + threadIdx.x;    // chunk of 8 elements
    int slot = g >> 7, c = g & 127;
    const int* offs = meta + 128;
    int e = (slot >= offs[1]) + (slot >= offs[2]) + (slot >= offs[3]);
    bool valid = slot < offs[e] + meta[e * 16];
    uint2 v;
    if (!valid) {
        v.x = 0u; v.y = 0u;
    } else {
        int src = perm[slot];
        const float* fp = F + (size_t)src * 1024 + c * 8;
        int w0 = 0, w1 = 0;
        w0 = __builtin_amdgcn_cvt_pk_fp8_f32(fp[0], fp[1], w0, false);
        w0 = __builtin_amdgcn_cvt_pk_fp8_f32(fp[2], fp[3], w0, true);
        w1 = __builtin_amdgcn_cvt_pk_fp8_f32(fp[4], fp[5], w1, false);
        w1 = __builtin_amdgcn_cvt_pk_fp8_f32(fp[6], fp[7], w1, true);
        v.x = (unsigned)w0; v.y = (unsigned)w1;
    }
    *(uint2*)(void*)(Xp + (size_t)g * 8) = v;
}

// -------- W [E][K][N] fp32 -> WT [E][N][K] fp8 of 32*W (z: 0=W1,1=W2) --------
__global__ void k_transw(const float* __restrict__ W1, u8* __restrict__ W1T,
                         const float* __restrict__ W2, u8* __restrict__ W2T) {
    __shared__ u8 tile[64][65];
    const float* W  = blockIdx.z ? W2  : W1;
    u8*          WT = blockIdx.z ? W2T : W1T;
    int e  = blockIdx.y;
    int tn = blockIdx.x & 15;
    int tk = blockIdx.x >> 4;
    const float* Wp = W  + (size_t)e * 1024 * 1024;
    u8*         WTp = WT + (size_t)e * 1024 * 1024;
    int c = threadIdx.x & 63, r0 = threadIdx.x >> 6;
#pragma unroll
    for (int i = 0; i < 16; ++i) {
        int r = r0 + i * 4;
        tile[r][c] = f2fp8(32.0f * Wp[(size_t)(tk * 64 + r) * 1024 + tn * 64 + c]);
    }
    __syncthreads();
#pragma unroll
    for (int i = 0; i < 16; ++i) {
        int r = r0 + i * 4;
        WTp[(size_t)(tn * 64 + r) * 1024 + tk * 64 + c] = tile[c][r];
    }
}

// ---------------- MX-fp8 MFMA GEMM: relu(A * (32B)^T * 2^-5 + bias) ----------------
// R9 structure: 256x256 tile, BK=128, 8 waves (2Mx4N, 128x64 per wave),
// double-buffered 128 KiB LDS, COUNTED vmcnt (T4) across RAW s_barrier
// (no __syncthreads drain in the main loop), s_setprio around MFMA clusters (T5).
// Rationale: R7's 128^2 structure drains vmcnt(0) at every K-step barrier
// (m97-structure ceiling); at K=1024 that drain dominated (~480 TF effective).
// Here tile kt+1's 8 global_load_lds stay in flight under tile kt's 16 MFMAs.
// Race-freedom: B1 barrier guarantees all waves finished reading buf[cur^1]
// (prev iter) before we issue loads into it; vmcnt(8) + B2 barrier guarantee
// tile kt fully landed in buf[cur] before any wave reads it.
// LDS swizzle (unchanged math): 16B chunk c of row r holds global chunk c^(r&7).
// XCD swizzle: 528 blocks = 66*8, chunked bijective; nt fastest within an XCD
// so 4 consecutive blocks share one A-panel (L2 reuse).
// FUSE=false: store fp8 C.  FUSE=true: fold layer3 dot + slope + global sum.
template <bool FUSE>
__global__ __launch_bounds__(512, 2)
void k_gemm(const u8* __restrict__ A, const u8* __restrict__ BT,
            const float* __restrict__ bias, u8* __restrict__ C,
            const int* __restrict__ meta, const float* __restrict__ W3,
            const float* __restrict__ slope, float* __restrict__ out) {
    __shared__ u8 As[2][32768];
    __shared__ u8 Bs[2][32768];
    const int* offs = meta + 128;

    // grid = dim3(8, 66) -> flat 0..527; XCD = flat&7 gets contiguous wgid chunk
    const int flat = blockIdx.y * 8 + blockIdx.x;
    const int wgid = (flat & 7) * 66 + (flat >> 3);
    const int mt = wgid >> 2;                  // m tile (0..131)
    const int nt = wgid & 3;                   // n tile (0..3), fast index
    const int m0 = mt * 256, n0 = nt * 256;
    if (m0 >= meta[132]) return;               // beyond actual padded M
    const int e = (m0 >= offs[1]) + (m0 >= offs[2]) + (m0 >= offs[3]);

    const int t = threadIdx.x;                 // 0..511
    const int w = t >> 6, lane = t & 63;
    const int l31 = lane & 31, khalf = lane >> 5;
    const int wm = w & 1, wn = w >> 1;         // 2x4 waves, each 128x64

    const u8* Ag = A  + (size_t)m0 * 1024;
    const u8* Bg = BT + (size_t)e * 1024 * 1024 + (size_t)n0 * 1024;

    // staging: per matrix per K-tile 4 instrs; instr i covers rows i*64+(t>>3),
    // 16B chunk t&7, swizzled source chunk (t&7)^(row&7); LDS stays linear.
    const int srow = t >> 3;                   // 0..63
    const int gcol = ((t & 7) ^ (srow & 7)) * 16;

    f32x16 acc[4][2] = {};

#define STAGE(buf, kt)                                                          \
    do {                                                                        \
        const size_t kb = (size_t)(kt) * 128;                                   \
        _Pragma("unroll")                                                       \
        for (int i = 0; i < 4; ++i) {                                           \
            __builtin_amdgcn_global_load_lds(                                   \
                (const void*)(Ag + (size_t)(i * 64 + srow) * 1024 + kb + gcol), \
                (void*)(&As[buf][i * 8192 + w * 1024]), 16, 0, 0);              \
            __builtin_amdgcn_global_load_lds(                                   \
                (const void*)(Bg + (size_t)(i * 64 + srow) * 1024 + kb + gcol), \
                (void*)(&Bs[buf][i * 8192 + w * 1024]), 16, 0, 0);              \
        }                                                                       \
    } while (0)

    STAGE(0, 0);                               // prologue: tile 0 -> buf 0

#pragma unroll 2
    for (int kt = 0; kt < 8; ++kt) {
        const int cur = kt & 1;
        // B1: all waves done reading buf[cur^1] (previous iteration)
        asm volatile("" ::: "memory");
        __builtin_amdgcn_s_barrier();
        asm volatile("" ::: "memory");
        if (kt < 7) {
            STAGE(cur ^ 1, kt + 1);            // prefetch next tile
            asm volatile("s_waitcnt vmcnt(8)" ::: "memory");   // tile kt landed
        } else {
            asm volatile("s_waitcnt vmcnt(0)" ::: "memory");
        }
        // B2: tile kt visible to every wave
        __builtin_amdgcn_s_barrier();
        asm volatile("" ::: "memory");

        const u8* Ab = &As[cur][0];
        const u8* Bb = &Bs[cur][0];

        // B fragments for the whole K-tile (2 ni x 2 ks): 32 VGPRs, reused by all mi
        i32x8 b[2][2];
#pragma unroll
        for (int ni = 0; ni < 2; ++ni)
#pragma unroll
            for (int ks = 0; ks < 2; ++ks) {
                int n = wn * 64 + ni * 32 + l31;
                int c0 = 4 * ks + 2 * khalf;
                const u8* base = Bb + n * 128;
                int lo = ((c0 ^ (n & 7)) << 4);
                union { uint4 q[2]; i32x8 v; } u;
                u.q[0] = *(const uint4*)(const void*)(base + lo);
                u.q[1] = *(const uint4*)(const void*)(base + (lo ^ 16));
                b[ni][ks] = u.v;
            }

#pragma unroll
        for (int mi = 0; mi < 4; ++mi) {
            i32x8 a[2];
#pragma unroll
            for (int ks = 0; ks < 2; ++ks) {
                int m = wm * 128 + mi * 32 + l31;
                int c0 = 4 * ks + 2 * khalf;
                const u8* base = Ab + m * 128;
                int lo = ((c0 ^ (m & 7)) << 4);
                union { uint4 q[2]; i32x8 v; } u;
                u.q[0] = *(const uint4*)(const void*)(base + lo);
                u.q[1] = *(const uint4*)(const void*)(base + (lo ^ 16));
                a[ks] = u.v;
            }
            __builtin_amdgcn_s_setprio(1);
#pragma unroll
            for (int ni = 0; ni < 2; ++ni)
#pragma unroll
                for (int ks = 0; ks < 2; ++ks)
                    acc[mi][ni] = __builtin_amdgcn_mfma_scale_f32_32x32x64_f8f6f4(
                        a[ks], b[ni][ks], acc[mi][ni],
                        0, 0,                       // cbsz=fp8(e4m3), blgp=fp8(e4m3)
                        0, 0x7F7F7F7F,              // A scale 2^0
                        0, 0x7A7A7A7A);             // B scale 2^-5 (undo 32*W)
            __builtin_amdgcn_s_setprio(0);
        }
    }
#undef STAGE

    // epilogue.  32x32 C/D layout: col=lane&31, row=(reg&3)+8*(reg>>2)+4*(lane>>5)
    if (!FUSE) {
#pragma unroll
        for (int ni = 0; ni < 2; ++ni) {
            int col = n0 + wn * 64 + ni * 32 + l31;
            float bv = bias[e * 1024 + col];
#pragma unroll
            for (int mi = 0; mi < 4; ++mi) {
                int rowb = m0 + wm * 128 + mi * 32 + 4 * khalf;
#pragma unroll
                for (int reg = 0; reg < 16; ++reg) {
                    int rowg = rowb + (reg & 3) + 8 * (reg >> 2);
                    float v = acc[mi][ni][reg] + bv;
                    v = v > 0.f ? v : 0.f;
                    C[(size_t)rowg * 1024 + col] = f2fp8(v);
                }
            }
        }
    } else {
        const int segEnd = offs[e] + meta[e * 16];   // valid slots < segEnd
        const float se = slope[e];
        float psum = 0.f;
#pragma unroll
        for (int ni = 0; ni < 2; ++ni) {
            int col = n0 + wn * 64 + ni * 32 + l31;
            float bv  = bias[e * 1024 + col];
            float w3s = W3[e * 1024 + col] * se;
#pragma unroll
            for (int mi = 0; mi < 4; ++mi) {
                int rowb = m0 + wm * 128 + mi * 32 + 4 * khalf;
#pragma unroll
                for (int reg = 0; reg < 16; ++reg) {
                    int rowg = rowb + (reg & 3) + 8 * (reg >> 2);
                    float v = acc[mi][ni][reg] + bv;
                    v = v > 0.f ? v : 0.f;
                    psum += (rowg < segEnd) ? v * w3s : 0.f;
                }
            }
        }
#pragma unroll
        for (int o = 32; o; o >>= 1) psum += __shfl_xor(psum, o, 64);
        __syncthreads();                     // all waves done with LDS reads
        float* red = (float*)As;
        if (lane == 0) red[w] = psum;
        __syncthreads();
        if (t == 0) {
            float s = 0.f;
#pragma unroll
            for (int i = 0; i < 8; ++i) s += red[i];
            atomicAdd(out, s);
        }
    }
}

extern "C" void kernel_launch(void* const* d_in, const int* in_sizes, int n_in,
                              void* d_out, int out_size, void* d_ws, size_t ws_size,
                              hipStream_t stream) {
    const float* features = (const float*)d_in[0];
    const int*   sym      = (const int*)d_in[1];
    const float* W1       = (const float*)d_in[2];
    const float* b1       = (const float*)d_in[3];
    const float* W2       = (const float*)d_in[4];
    const float* b2       = (const float*)d_in[5];
    const float* W3       = (const float*)d_in[6];
    const float* b3       = (const float*)d_in[7];
    const float* slope    = (const float*)d_in[8];
    const float* inter    = (const float*)d_in[9];
    float* out = (float*)d_out;

    char* ws  = (char*)d_ws;
    u8*  Xp   = (u8*)(ws + XP_OFF);
    u8*  H1b  = (u8*)(ws + H1_OFF);
    u8*  W1T  = (u8*)(ws + W1T_OFF);
    u8*  W2T  = (u8*)(ws + W2T_OFF);
    int* perm = (int*)(ws + PERM_OFF);
    int* meta = (int*)(ws + META_OFF);

    k_count<<<NATOMS / 256, 256, 0, stream>>>(sym, meta);
    k_offsets<<<1, 256, 0, stream>>>(meta, slope, b3, inter, out);
    k_scatter<<<NATOMS / 256, 256, 0, stream>>>(sym, meta, perm);
    k_convx<<<(MCAP * 128) / 256, 256, 0, stream>>>(features, perm, meta, Xp);
    k_transw<<<dim3(256, 4, 2), 256, 0, stream>>>(W1, W1T, W2, W2T);
    k_gemm<false><<<dim3(8, 66), 512, 0, stream>>>(Xp, W1T, b1, H1b, meta,
                                                   nullptr, nullptr, nullptr);
    k_gemm<true><<<dim3(8, 66), 512, 0, stream>>>(H1b, W2T, b2, nullptr, meta,
                                                  W3, slope, out);
}